// Round 1
// baseline (218.007 us; speedup 1.0000x reference)
//
#include <hip/hip_runtime.h>
#include <math.h>

// Problem constants (from reference): N=16384, circular conv along last dim.
#define NN 16384
#define TILE 256
#define HALO 10
#define NBLK_PER_ROW (NN / TILE)

__device__ __forceinline__ float elu_f(float v) {
    return v > 0.0f ? v : (__expf(v) - 1.0f);
}

__global__ __launch_bounds__(256)
void smag_kernel(const float* __restrict__ x,
                 const float* __restrict__ dw,   // [5]  deriv weights (already /dx)
                 const float* __restrict__ fw,   // [3]  box filter
                 const float* __restrict__ W1, const float* __restrict__ b1,  // [6,2,5],[6]
                 const float* __restrict__ W2, const float* __restrict__ b2,  // [3,6,5],[3]
                 const float* __restrict__ W3, const float* __restrict__ b3,  // [1,3,5],[1]
                 float* __restrict__ out)
{
    const int tile = blockIdx.x & (NBLK_PER_ROW - 1);
    const int row  = blockIdx.x >> 6;              // 64 tiles per row
    const int base = tile * TILE;
    const float* __restrict__ xr  = x   + (size_t)row * NN;
    float* __restrict__ outr      = out + (size_t)row * NN;
    const int tid = threadIdx.x;

    __shared__ float sx [TILE + 2*HALO];   // x at [base-10, base+T+10)
    __shared__ float sxd[TILE + 16];       // xdiff at [-8, T+8)
    __shared__ float sf1[TILE + 16];       // feat ch1 = x - box(x), same range
    __shared__ float sh1[6][TILE + 12];    // h1 at [-6, T+6)
    __shared__ float sh2[3][TILE + 8];     // h2 at [-4, T+4)
    __shared__ float sy [TILE + 4];        // sqrt2*y at [-2, T+2)

    // ---- load x with halo (circular, N is pow2) ----
    for (int i = tid; i < TILE + 2*HALO; i += 256) {
        int g = (base + i - HALO + NN) & (NN - 1);
        sx[i] = xr[g];
    }
    __syncthreads();

    // ---- stage 1: xdiff + feat ch1 on [-8, T+8) ----
    const float d0 = dw[0], d1 = dw[1], d2 = dw[2], d3 = dw[3], d4 = dw[4];
    const float f0 = fw[0], f1 = fw[1], f2 = fw[2];
    for (int i = tid; i < TILE + 16; i += 256) {
        const int p = i + 2;  // sx index of center position
        float xm2 = sx[p-2], xm1 = sx[p-1], x0 = sx[p], xp1 = sx[p+1], xp2 = sx[p+2];
        sxd[i] = d0*xm2 + d1*xm1 + d2*x0 + d3*xp1 + d4*xp2;
        sf1[i] = x0 - (f0*xm1 + f1*x0 + f2*xp1);
    }
    __syncthreads();

    // ---- stage 2: h1 = elu(conv(feat, W1) + b1) on [-6, T+6) ----
    for (int i = tid; i < TILE + 12; i += 256) {
        float acc[6];
        #pragma unroll
        for (int c = 0; c < 6; ++c) acc[c] = b1[c];
        #pragma unroll
        for (int k = 0; k < 5; ++k) {
            const float v0 = sxd[i + k];   // feat ch0 at pos center+k-2
            const float v1 = sf1[i + k];   // feat ch1
            #pragma unroll
            for (int c = 0; c < 6; ++c) {
                acc[c] += W1[c*10 + k] * v0 + W1[c*10 + 5 + k] * v1;
            }
        }
        #pragma unroll
        for (int c = 0; c < 6; ++c) sh1[c][i] = elu_f(acc[c]);
    }
    __syncthreads();

    // ---- stage 3: h2 = elu(conv(h1, W2) + b2) on [-4, T+4) ----
    for (int i = tid; i < TILE + 8; i += 256) {
        float acc[3];
        #pragma unroll
        for (int c = 0; c < 3; ++c) acc[c] = b2[c];
        #pragma unroll
        for (int k = 0; k < 5; ++k) {
            #pragma unroll
            for (int ci = 0; ci < 6; ++ci) {
                const float v = sh1[ci][i + k];
                #pragma unroll
                for (int c = 0; c < 3; ++c) {
                    acc[c] += W2[c*30 + ci*5 + k] * v;
                }
            }
        }
        #pragma unroll
        for (int c = 0; c < 3; ++c) sh2[c][i] = elu_f(acc[c]);
    }
    __syncthreads();

    // ---- stage 4: cs -> y (with sqrt2 folded) on [-2, T+2) ----
    const float b3v = b3[0];
    const float CUTOFF = 2.0f / 16384.0f;     // 2*dx
    const float SQRT2 = 1.41421356237309515f;
    for (int i = tid; i < TILE + 4; i += 256) {
        float acc = b3v;
        #pragma unroll
        for (int k = 0; k < 5; ++k) {
            #pragma unroll
            for (int ci = 0; ci < 3; ++ci) {
                acc += W3[ci*5 + k] * sh2[ci][i + k];
            }
        }
        float cs = elu_f(acc);
        cs = fminf(fmaxf(cs, 0.0f), 1.0f);
        const float xd = sxd[i + 6];          // xdiff at this position
        const float t = cs * CUTOFF;
        sy[i] = SQRT2 * t * t * fabsf(xd) * xd;
    }
    __syncthreads();

    // ---- stage 5: out = conv(sqrt2*y, dw) on [0, T) ----
    for (int i = tid; i < TILE; i += 256) {
        float acc = d0*sy[i] + d1*sy[i+1] + d2*sy[i+2] + d3*sy[i+3] + d4*sy[i+4];
        outr[base + i] = acc;
    }
}

extern "C" void kernel_launch(void* const* d_in, const int* in_sizes, int n_in,
                              void* d_out, int out_size, void* d_ws, size_t ws_size,
                              hipStream_t stream) {
    const float* x  = (const float*)d_in[0];
    const float* dw = (const float*)d_in[1];
    const float* fw = (const float*)d_in[2];
    const float* W1 = (const float*)d_in[3];
    const float* b1 = (const float*)d_in[4];
    const float* W2 = (const float*)d_in[5];
    const float* b2 = (const float*)d_in[6];
    const float* W3 = (const float*)d_in[7];
    const float* b3 = (const float*)d_in[8];
    float* out = (float*)d_out;

    const int B = 1024;
    dim3 grid(B * NBLK_PER_ROW);
    dim3 block(256);
    hipLaunchKernelGGL(smag_kernel, grid, block, 0, stream,
                       x, dw, fw, W1, b1, W2, b2, W3, b3, out);
}